// Round 15
// baseline (202.789 us; speedup 1.0000x reference)
//
#include <hip/hip_runtime.h>
#include <hip/hip_bf16.h>

#define NTOK 8192
#define HDIM 768
#define IDIM 2048
#define NEXP 8
#define BM 128
#define BN 128
#define BK 64
#define LIST_CAP 17408   // sum_e roundup(cnt[e],128) <= 2T + 8*128
#define MAXTILES 136     // sum_e ceil(cnt[e]/128) <= 128 + 8

// ---- ws layout (byte offsets) ---- (round-5/9 verified layout)
#define WS_CNT    0u
#define WS_OFFP   64u
#define WS_RUN    96u
#define WS_NTIL   128u
#define WS_TTAB   192u
#define WS_CNT2   768u        // int[8*16] — one counter per 64B cacheline
#define WS_IMP    1280u       // float[256*8]
#define WS_CNTP   9472u       // int[256*8]
#define WS_TOPKI  17664u      // uchar2[NTOK]
#define WS_TOPKP  34048u      // float[NTOK*2] (overlaid by WS_TG after build_lists)
#define WS_TG     34048u      // int2[NTOK] — overlays TOPKP (same 8B, same thread)
#define WS_LTOK   99584u      // int[LIST_CAP]
#define WS_LW     169216u     // float[LIST_CAP]
#define WS_XB     238848u     // ushort bf16 [NTOK*HDIM]
#define WS_W1B    12821760u   // ushort bf16 [NEXP*IDIM*HDIM]
#define WS_W2B    37987584u   // ushort bf16 [NEXP*HDIM*IDIM]
#define WS_H      63153408u   // ushort bf16 [LIST_CAP*IDIM]
#define WS_SEL    238848u     // ushort bf16 [LIST_CAP*HDIM] — reuses XB+W1B (dead after gemm1)
#define WS_NEEDED 134456576u  // verified rounds 4-9

typedef __attribute__((ext_vector_type(8))) __bf16 bf16x8;
typedef __attribute__((ext_vector_type(4))) float f32x4;

__device__ __forceinline__ unsigned short f2bf(float f) {
  unsigned int u = __float_as_uint(f);
  u += 0x7FFFu + ((u >> 16) & 1u);   // RNE (inputs finite)
  return (unsigned short)(u >> 16);
}
__device__ __forceinline__ float bf2f(unsigned short u) {
  return __uint_as_float(((unsigned int)u) << 16);
}

__device__ __forceinline__ void gload_lds16(const void* g, void* l) {
  __builtin_amdgcn_global_load_lds(
      (const __attribute__((address_space(1))) void*)g,
      (__attribute__((address_space(3))) void*)l, 16, 0, 0);
}

// ------------- fused fp32 -> bf16 conversion of w1 AND w2 (one dispatch) ----
#define W1_N8 (NEXP * IDIM * HDIM / 8)   // 1572864
#define W2_N8 (NEXP * HDIM * IDIM / 8)   // 1572864
__global__ void cvt_w_kernel(const float* __restrict__ w1,
                             const float* __restrict__ w2,
                             char* __restrict__ ws) {
  int stride = gridDim.x * blockDim.x;
  unsigned short* d1 = (unsigned short*)(ws + WS_W1B);
  unsigned short* d2 = (unsigned short*)(ws + WS_W2B);
  for (int i = blockIdx.x * blockDim.x + threadIdx.x; i < W1_N8 + W2_N8; i += stride) {
    const float4* s4;
    uint4* d4;
    if (i < W1_N8) { s4 = (const float4*)w1; d4 = (uint4*)d1; }
    else           { s4 = (const float4*)w2 - 2 * W1_N8; d4 = (uint4*)d2 - W1_N8; }
    float4 a = s4[2 * i];
    float4 b = s4[2 * i + 1];
    uint4 o;
    o.x = (unsigned)f2bf(a.x) | ((unsigned)f2bf(a.y) << 16);
    o.y = (unsigned)f2bf(a.z) | ((unsigned)f2bf(a.w) << 16);
    o.z = (unsigned)f2bf(b.x) | ((unsigned)f2bf(b.y) << 16);
    o.w = (unsigned)f2bf(b.z) | ((unsigned)f2bf(b.w) << 16);
    d4[i] = o;
  }
}

// ------------- router: 32 tokens/block, 256 blocks; fused x->bf16 -------------
__global__ __launch_bounds__(256) void router_kernel(
    const float* __restrict__ x, const float* __restrict__ rw,
    char* __restrict__ ws) {
  __shared__ float rws[NEXP * HDIM];  // 24KB
  __shared__ float lg[32][NEXP];
  const int tid = threadIdx.x;
  const int t0 = blockIdx.x * 32;
  {  // fused conversion of this block's x chunk
    const float4* xs = (const float4*)(x + (size_t)t0 * HDIM);
    uint4* xd = (uint4*)((unsigned short*)(ws + WS_XB) + (size_t)t0 * HDIM);
    for (int i = tid; i < 32 * HDIM / 8; i += 256) {
      float4 a = xs[2 * i];
      float4 b = xs[2 * i + 1];
      uint4 o;
      o.x = (unsigned)f2bf(a.x) | ((unsigned)f2bf(a.y) << 16);
      o.y = (unsigned)f2bf(a.z) | ((unsigned)f2bf(a.w) << 16);
      o.z = (unsigned)f2bf(b.x) | ((unsigned)f2bf(b.y) << 16);
      o.w = (unsigned)f2bf(b.z) | ((unsigned)f2bf(b.w) << 16);
      xd[i] = o;
    }
  }
  for (int i = tid; i < NEXP * HDIM / 4; i += 256)
    ((float4*)rws)[i] = ((const float4*)rw)[i];
  __syncthreads();
  {  // 256 (token,expert) dots, 1 per thread (x re-read hits L2)
    const int m = tid >> 3, e = tid & 7;
    const float* xr = x + (size_t)(t0 + m) * HDIM;
    const float* wr = rws + e * HDIM;
    float acc = 0.f;
    for (int h = 0; h < HDIM; h += 4) {
      float4 xv = *(const float4*)(xr + h);
      acc += xv.x * wr[h] + xv.y * wr[h + 1] + xv.z * wr[h + 2] + xv.w * wr[h + 3];
    }
    lg[m][e] = acc;
  }
  __syncthreads();
  if (tid < 32) {  // lanes 0..31 of wave 0: softmax + top2 + partials
    const int m = tid;
    float pr[8], mx = -1e30f;
    for (int e = 0; e < 8; e++) { pr[e] = lg[m][e]; mx = fmaxf(mx, pr[e]); }
    float s = 0.f;
    for (int e = 0; e < 8; e++) { pr[e] = __expf(pr[e] - mx); s += pr[e]; }
    float inv = 1.f / s;
    for (int e = 0; e < 8; e++) pr[e] *= inv;
    int i0 = 0;
    for (int e = 1; e < 8; e++) if (pr[e] > pr[i0]) i0 = e;
    int i1 = (i0 == 0) ? 1 : 0;
    for (int e = 0; e < 8; e++) if (e != i0 && pr[e] > pr[i1]) i1 = e;
    const int t = t0 + m;
    ((uchar2*)(ws + WS_TOPKI))[t] = make_uchar2((unsigned char)i0, (unsigned char)i1);
    ((float*)(ws + WS_TOPKP))[2 * t] = pr[i0];
    ((float*)(ws + WS_TOPKP))[2 * t + 1] = pr[i1];
    float* ip = (float*)(ws + WS_IMP) + blockIdx.x * 8;
    int* cp = (int*)(ws + WS_CNTP) + blockIdx.x * 8;
    for (int e = 0; e < 8; e++) {
      float v = pr[e];
      for (int off = 16; off; off >>= 1) v += __shfl_down(v, off);  // lanes 0..31
      unsigned long long b0 = __ballot(i0 == e);
      unsigned long long b1 = __ballot(i1 == e);
      if (tid == 0) { ip[e] = v; cp[e] = __popcll(b0) + __popcll(b1); }
    }
  }
}

// ---- finalize: PARALLEL partial reduction (64 thr), serial prefix tail -----
// 8 partials per expert x 32 blocks each; 3-step shfl_down tree is clean at
// the base lane of each 8-lane group (only base-lane results are consumed).
__global__ void finalize_kernel(char* __restrict__ ws) {
  __shared__ int scnt[8];
  const int tid = threadIdx.x;          // 64 threads, one wave
  const int e = tid >> 3, part = tid & 7;
  const float* ip = (const float*)(ws + WS_IMP);
  const int* cp = (const int*)(ws + WS_CNTP);
  float s = 0.f; int c = 0;
  for (int b = part * 32; b < part * 32 + 32; b++) {
    s += ip[b * 8 + e];
    c += cp[b * 8 + e];
  }
  for (int off = 4; off; off >>= 1) {
    s += __shfl_down(s, off);
    c += __shfl_down(c, off);
  }
  if (part == 0) {
    float running = 1.0f;
    float blended = running + 0.1f * (s - running);
    ((float*)(ws + WS_RUN))[e] = blended + 0.01f;
    ((int*)(ws + WS_CNT))[e] = c;
    ((int*)(ws + WS_CNT2))[e * 16] = 0;   // padded counters, 1 per cacheline
    scnt[e] = c;
  }
  __syncthreads();
  if (tid == 0) {
    int* offp = (int*)(ws + WS_OFFP);
    int* ttab = (int*)(ws + WS_TTAB);
    int o = 0, n = 0;
    for (int e2 = 0; e2 < 8; e2++) {
      offp[e2] = o;
      int tl = (scnt[e2] + BM - 1) / BM;
      o += tl * BM;
      for (int r = 0; r < tl; r++) ttab[n++] = (e2 << 8) | r;
    }
    *((int*)(ws + WS_NTIL)) = n;
  }
}

// ------- build lists: wave-aggregated ballot ranks, 1 atomic/(wave,expert) --
__global__ __launch_bounds__(256) void build_lists(char* __restrict__ ws) {
  const int t = blockIdx.x * blockDim.x + threadIdx.x;
  const int lane = threadIdx.x & 63;
  const uchar2* ti = (const uchar2*)(ws + WS_TOPKI);
  const float* tp = (const float*)(ws + WS_TOPKP);
  const float* run = (const float*)(ws + WS_RUN);
  int* cnt2 = (int*)(ws + WS_CNT2);
  const int* offp = (const int*)(ws + WS_OFFP);
  int* ltok = (int*)(ws + WS_LTOK);
  float* lw = (float*)(ws + WS_LW);
  const uchar2 ee = ti[t];
  const int e0 = ee.x, e1 = ee.y;
  const float b0 = tp[2 * t] / run[e0], b1 = tp[2 * t + 1] / run[e1];
  const float inv = 1.f / (b0 + b1);
  const unsigned long long lt = (1ull << lane) - 1ull;
  int g0 = 0, g1 = 0;
#pragma unroll
  for (int e = 0; e < 8; e++) {
    unsigned long long m0 = __ballot(e0 == e);
    unsigned long long m1 = __ballot(e1 == e);
    const int c0 = __popcll(m0);
    const int ctot = c0 + __popcll(m1);
    int base = 0;
    if (lane == 0 && ctot) base = atomicAdd(&cnt2[e * 16], ctot);
    base = __shfl(base, 0);
    if (e0 == e) g0 = offp[e] + base + __popcll(m0 & lt);
    if (e1 == e) g1 = offp[e] + base + c0 + __popcll(m1 & lt);
  }
  ltok[g0] = t; lw[g0] = b0 * inv;
  ltok[g1] = t; lw[g1] = b1 * inv;
  // overlay: WS_TG[t] occupies exactly tp[2t..2t+1] which this thread has read
  ((int2*)(ws + WS_TG))[t] = make_int2(g0, g1);
}

// ======== pipelined GEMM core (round-5 proven form, counted vmcnt) ========
#define GEMM_PIPELINE(NK)                                                      \
  {                                                                            \
    stage(0, 0);                                                               \
    stage(1, 1);                                                               \
    asm volatile("s_waitcnt vmcnt(8)" ::: "memory");                           \
    __builtin_amdgcn_sched_barrier(0);                                         \
    asm volatile("s_barrier" ::: "memory");                                    \
    int cur = 0;                                                               \
    for (int t = 0; t < (NK); ++t) {                                           \
      bf16x8 af[2][4], bg[2][4];                                               \
      const unsigned short* rA = &SB[cur][0][0];                               \
      const unsigned short* rB = &SB[cur][1][0];                               \
      _Pragma("unroll") for (int ks = 0; ks < 2; ks++) {                       \
        const int sl = ((ks * 4 + hi) ^ (fr & 7)) * 8;                         \
        _Pragma("unroll") for (int i = 0; i < 4; i++)                          \
            af[ks][i] = *(const bf16x8*)&rA[(wr + i * 16 + fr) * BK + sl];     \
        _Pragma("unroll") for (int j = 0; j < 4; j++)                          \
            bg[ks][j] = *(const bf16x8*)&rB[(wc + j * 16 + fr) * BK + sl];     \
      }                                                                        \
      asm volatile("s_waitcnt lgkmcnt(0)" ::: "memory"); /* my reads done */   \
      __builtin_amdgcn_sched_barrier(0);                                       \
      asm volatile("s_barrier" ::: "memory");            /* all reads done */  \
      if (t + 2 < (NK)) stage(cur, t + 2);                                     \
      __builtin_amdgcn_s_setprio(1);                                           \
      _Pragma("unroll") for (int ks = 0; ks < 2; ks++)                         \
          _Pragma("unroll") for (int i = 0; i < 4; i++)                        \
              _Pragma("unroll") for (int j = 0; j < 4; j++)                    \
                  acc[i][j] = __builtin_amdgcn_mfma_f32_16x16x32_bf16(         \
                      af[ks][i], bg[ks][j], acc[i][j], 0, 0, 0);               \
      __builtin_amdgcn_s_setprio(0);                                           \
      if (t + 2 < (NK)) {                                                      \
        asm volatile("s_waitcnt vmcnt(8)" ::: "memory"); /* t+1 landed */      \
      } else {                                                                 \
        asm volatile("s_waitcnt vmcnt(0)" ::: "memory"); /* tail drain */      \
      }                                                                        \
      __builtin_amdgcn_sched_barrier(0);                                       \
      asm volatile("s_barrier" ::: "memory");            /* t+1 ready */       \
      cur ^= 1;                                                                \
    }                                                                          \
  }

// ---------------- GEMM1: h = silu(x_gather @ w1_e^T), K=768 ----------------
__global__ __launch_bounds__(256) void gemm1_kernel(char* __restrict__ ws) {
  __shared__ unsigned short SB[2][2][BM * BK];  // 64KB: [dbuf][A/B][128][64]
  const int nt = *(const int*)(ws + WS_NTIL);
  const int nbx = IDIM / BN;                    // 16
  int bid = blockIdx.y * nbx + blockIdx.x;
  const int chunk = (nbx * MAXTILES) >> 3;      // 2176/8 = 272, bijective
  bid = (bid & 7) * chunk + (bid >> 3);
  const int bx = bid % nbx, by = bid / nbx;
  if (by >= nt) return;
  const int tile = ((const int*)(ws + WS_TTAB))[by];
  const int e = tile >> 8, rt = tile & 255;
  const int ce = ((const int*)(ws + WS_CNT))[e];
  const int base = ((const int*)(ws + WS_OFFP))[e];
  const int* __restrict__ ltok = (const int*)(ws + WS_LTOK);
  const unsigned short* __restrict__ xb = (const unsigned short*)(ws + WS_XB);
  const unsigned short* __restrict__ w1b =
      (const unsigned short*)(ws + WS_W1B) + (size_t)e * IDIM * HDIM;
  unsigned short* __restrict__ hb = (unsigned short*)(ws + WS_H);

  const int tid = threadIdx.x;
  const int lane = tid & 63, wave = tid >> 6;
  const int lr = tid >> 3;                               // staging row 0..31
  const int ko_sw = ((tid & 7) ^ (lr & 7)) * 8;          // source-side XOR swizzle
  const int n0 = bx * BN;

  const unsigned short* ga[4];
  const unsigned short* gb[4];
#pragma unroll
  for (int c = 0; c < 4; c++) {
    int s = rt * BM + c * 32 + lr; s = (s < ce) ? s : (ce - 1);
    ga[c] = xb + (size_t)ltok[base + s] * HDIM + ko_sw;
    gb[c] = w1b + (size_t)(n0 + c * 32 + lr) * HDIM + ko_sw;
  }

  auto stage = [&](int buf, int kt) {
    unsigned short* dA = &SB[buf][0][wave * 512];
    unsigned short* dB = &SB[buf][1][wave * 512];
#pragma unroll
    for (int c = 0; c < 4; c++) {
      gload_lds16(ga[c] + kt * BK, dA + c * 2048);
      gload_lds16(gb[c] + kt * BK, dB + c * 2048);
    }
  };

  f32x4 acc[4][4];
#pragma unroll
  for (int i = 0; i < 4; i++)
#pragma unroll
    for (int j = 0; j < 4; j++) acc[i][j] = (f32x4){0.f, 0.f, 0.f, 0.f};

  const int wr = (wave >> 1) * 64, wc = (wave & 1) * 64;
  const int fr = lane & 15, hi = lane >> 4;

  GEMM_PIPELINE(HDIM / BK)

  const int rq = (lane >> 4) * 4;
#pragma unroll
  for (int i = 0; i < 4; i++) {
#pragma unroll
    for (int r = 0; r < 4; r++) {
      const int slot = rt * BM + wr + i * 16 + rq + r;
      unsigned short* hrow = hb + (size_t)(base + slot) * IDIM + n0 + wc;
#pragma unroll
      for (int j = 0; j < 4; j++) {
        float v = acc[i][j][r];
        float sv = v / (1.f + __expf(-v));
        hrow[j * 16 + fr] = f2bf(sv);
      }
    }
  }
}

// ---------------- GEMM2: sel[g] = lw[g] * (h @ w2_e^T) (bf16), K=2048 ------
__global__ __launch_bounds__(256) void gemm2_kernel(char* __restrict__ ws) {
  __shared__ unsigned short SB[2][2][BM * BK];  // 64KB
  const int nt = *(const int*)(ws + WS_NTIL);
  const int nbx = HDIM / BN;                    // 6
  int bid = blockIdx.y * nbx + blockIdx.x;
  const int chunk = (nbx * MAXTILES) >> 3;      // 816/8 = 102, bijective
  bid = (bid & 7) * chunk + (bid >> 3);
  const int bx = bid % nbx, by = bid / nbx;
  if (by >= nt) return;
  const int tile = ((const int*)(ws + WS_TTAB))[by];
  const int e = tile >> 8, rt = tile & 255;
  const int ce = ((const int*)(ws + WS_CNT))[e];
  const int base = ((const int*)(ws + WS_OFFP))[e];
  const float* __restrict__ lw = (const float*)(ws + WS_LW);
  const unsigned short* __restrict__ hb = (const unsigned short*)(ws + WS_H);
  const unsigned short* __restrict__ w2b =
      (const unsigned short*)(ws + WS_W2B) + (size_t)e * HDIM * IDIM;
  unsigned short* __restrict__ selb = (unsigned short*)(ws + WS_SEL);

  const int tid = threadIdx.x;
  const int lane = tid & 63, wave = tid >> 6;
  const int lr = tid >> 3;
  const int ko_sw = ((tid & 7) ^ (lr & 7)) * 8;
  const int n0 = bx * BN;

  const unsigned short* ga[4];
  const unsigned short* gb[4];
#pragma unroll
  for (int c = 0; c < 4; c++) {
    ga[c] = hb + (size_t)(base + rt * BM + c * 32 + lr) * IDIM + ko_sw;  // pad rows defined
    gb[c] = w2b + (size_t)(n0 + c * 32 + lr) * IDIM + ko_sw;
  }

  auto stage = [&](int buf, int kt) {
    unsigned short* dA = &SB[buf][0][wave * 512];
    unsigned short* dB = &SB[buf][1][wave * 512];
#pragma unroll
    for (int c = 0; c < 4; c++) {
      gload_lds16(ga[c] + kt * BK, dA + c * 2048);
      gload_lds16(gb[c] + kt * BK, dB + c * 2048);
    }
  };

  f32x4 acc[4][4];
#pragma unroll
  for (int i = 0; i < 4; i++)
#pragma unroll
    for (int j = 0; j < 4; j++) acc[i][j] = (f32x4){0.f, 0.f, 0.f, 0.f};

  const int wr = (wave >> 1) * 64, wc = (wave & 1) * 64;
  const int fr = lane & 15, hi = lane >> 4;

  GEMM_PIPELINE(IDIM / BK)

  const int rq = (lane >> 4) * 4;
#pragma unroll
  for (int i = 0; i < 4; i++) {
#pragma unroll
    for (int r = 0; r < 4; r++) {
      const int slot = rt * BM + wr + i * 16 + rq + r;
      if (slot < ce) {
        const int g = base + slot;
        const float w = lw[g];                      // weight pre-applied before bf16
        unsigned short* srow = selb + (size_t)g * HDIM + n0 + wc;
#pragma unroll
        for (int j = 0; j < 4; j++)
          srow[j * 16 + fr] = f2bf(w * acc[i][j][r]);
      }
    }
  }
}

// ---------------- combine: out[t] = sel[g0] + sel[g1], 2 tokens/block -------
__global__ __launch_bounds__(384) void combine_kernel(const char* __restrict__ ws,
                                                      float* __restrict__ out) {
  const int t = blockIdx.x * 2 + (threadIdx.x >= 192);
  const int c = threadIdx.x - (threadIdx.x >= 192 ? 192 : 0);  // 0..191, 4 floats each
  const int2 g = ((const int2*)(ws + WS_TG))[t];
  const unsigned short* selb = (const unsigned short*)(ws + WS_SEL);
  ushort4 a = *(const ushort4*)(selb + (size_t)g.x * HDIM + c * 4);
  ushort4 b = *(const ushort4*)(selb + (size_t)g.y * HDIM + c * 4);
  float4 o;
  o.x = bf2f(a.x) + bf2f(b.x);
  o.y = bf2f(a.y) + bf2f(b.y);
  o.z = bf2f(a.z) + bf2f(b.z);
  o.w = bf2f(a.w) + bf2f(b.w);
  ((float4*)out)[(size_t)t * (HDIM / 4) + c] = o;
}

extern "C" void kernel_launch(void* const* d_in, const int* in_sizes, int n_in,
                              void* d_out, int out_size, void* d_ws, size_t ws_size,
                              hipStream_t stream) {
  const float* x = (const float*)d_in[0];
  const float* rw = (const float*)d_in[1];
  const float* w1 = (const float*)d_in[2];
  const float* w2 = (const float*)d_in[3];
  float* out = (float*)d_out;
  char* ws = (char*)d_ws;

  if (ws_size < (size_t)WS_NEEDED) {  // diagnostic path: zeros
    hipMemsetAsync(d_out, 0, (size_t)out_size * sizeof(float), stream);
    return;
  }

  cvt_w_kernel<<<2048, 256, 0, stream>>>(w1, w2, ws);
  router_kernel<<<NTOK / 32, 256, 0, stream>>>(x, rw, ws);
  finalize_kernel<<<1, 64, 0, stream>>>(ws);
  build_lists<<<NTOK / 256, 256, 0, stream>>>(ws);
  gemm1_kernel<<<dim3(IDIM / BN, MAXTILES), 256, 0, stream>>>(ws);
  gemm2_kernel<<<dim3(HDIM / BN, MAXTILES), 256, 0, stream>>>(ws);
  combine_kernel<<<NTOK / 2, 384, 0, stream>>>(ws, out);
}

// Round 16
// 202.235 us; speedup vs baseline: 1.0027x; 1.0027x over previous
//
#include <hip/hip_runtime.h>
#include <hip/hip_bf16.h>

#define NTOK 8192
#define HDIM 768
#define IDIM 2048
#define NEXP 8
#define BM 128
#define BN 128
#define BK 64
#define LIST_CAP 17408   // sum_e roundup(cnt[e],128) <= 2T + 8*128
#define MAXTILES 136     // sum_e ceil(cnt[e]/128) <= 128 + 8

// ---- ws layout (byte offsets) ---- (round-5/9 verified layout)
#define WS_CNT    0u
#define WS_OFFP   64u
#define WS_RUN    96u
#define WS_NTIL   128u
#define WS_TTAB   192u
#define WS_CNT2   768u        // int[8*16] — one counter per 64B cacheline
#define WS_IMP    1280u       // float[256*8]
#define WS_CNTP   9472u       // int[256*8]
#define WS_TOPKI  17664u      // uchar2[NTOK]
#define WS_TOPKP  34048u      // float[NTOK*2] (overlaid by WS_TG after build_lists)
#define WS_TG     34048u      // int2[NTOK] — overlays TOPKP (same 8B, same thread)
#define WS_LTOK   99584u      // int[LIST_CAP]
#define WS_LW     169216u     // float[LIST_CAP]
#define WS_XB     238848u     // ushort bf16 [NTOK*HDIM]
#define WS_W1B    12821760u   // ushort bf16 [NEXP*IDIM*HDIM]
#define WS_W2B    37987584u   // ushort bf16 [NEXP*HDIM*IDIM]
#define WS_H      63153408u   // ushort bf16 [LIST_CAP*IDIM]
#define WS_SEL    238848u     // ushort bf16 [LIST_CAP*HDIM] — reuses XB+W1B (dead after gemm1)
#define WS_NEEDED 134456576u  // verified rounds 4-9

typedef __attribute__((ext_vector_type(8))) __bf16 bf16x8;
typedef __attribute__((ext_vector_type(4))) float f32x4;

__device__ __forceinline__ unsigned short f2bf(float f) {
  unsigned int u = __float_as_uint(f);
  u += 0x7FFFu + ((u >> 16) & 1u);   // RNE (inputs finite)
  return (unsigned short)(u >> 16);
}
__device__ __forceinline__ float bf2f(unsigned short u) {
  return __uint_as_float(((unsigned int)u) << 16);
}

__device__ __forceinline__ void gload_lds16(const void* g, void* l) {
  __builtin_amdgcn_global_load_lds(
      (const __attribute__((address_space(1))) void*)g,
      (__attribute__((address_space(3))) void*)l, 16, 0, 0);
}

// ------------- fused fp32 -> bf16 conversion of w1 AND w2 (one dispatch) ----
#define W1_N8 (NEXP * IDIM * HDIM / 8)   // 1572864
#define W2_N8 (NEXP * HDIM * IDIM / 8)   // 1572864
__global__ void cvt_w_kernel(const float* __restrict__ w1,
                             const float* __restrict__ w2,
                             char* __restrict__ ws) {
  int stride = gridDim.x * blockDim.x;
  unsigned short* d1 = (unsigned short*)(ws + WS_W1B);
  unsigned short* d2 = (unsigned short*)(ws + WS_W2B);
  for (int i = blockIdx.x * blockDim.x + threadIdx.x; i < W1_N8 + W2_N8; i += stride) {
    const float4* s4;
    uint4* d4;
    if (i < W1_N8) { s4 = (const float4*)w1; d4 = (uint4*)d1; }
    else           { s4 = (const float4*)w2 - 2 * W1_N8; d4 = (uint4*)d2 - W1_N8; }
    float4 a = s4[2 * i];
    float4 b = s4[2 * i + 1];
    uint4 o;
    o.x = (unsigned)f2bf(a.x) | ((unsigned)f2bf(a.y) << 16);
    o.y = (unsigned)f2bf(a.z) | ((unsigned)f2bf(a.w) << 16);
    o.z = (unsigned)f2bf(b.x) | ((unsigned)f2bf(b.y) << 16);
    o.w = (unsigned)f2bf(b.z) | ((unsigned)f2bf(b.w) << 16);
    d4[i] = o;
  }
}

// ------------- router: 32 tokens/block, 256 blocks; fused x->bf16 -------------
__global__ __launch_bounds__(256) void router_kernel(
    const float* __restrict__ x, const float* __restrict__ rw,
    char* __restrict__ ws) {
  __shared__ float rws[NEXP * HDIM];  // 24KB
  __shared__ float lg[32][NEXP];
  const int tid = threadIdx.x;
  const int t0 = blockIdx.x * 32;
  {  // fused conversion of this block's x chunk
    const float4* xs = (const float4*)(x + (size_t)t0 * HDIM);
    uint4* xd = (uint4*)((unsigned short*)(ws + WS_XB) + (size_t)t0 * HDIM);
    for (int i = tid; i < 32 * HDIM / 8; i += 256) {
      float4 a = xs[2 * i];
      float4 b = xs[2 * i + 1];
      uint4 o;
      o.x = (unsigned)f2bf(a.x) | ((unsigned)f2bf(a.y) << 16);
      o.y = (unsigned)f2bf(a.z) | ((unsigned)f2bf(a.w) << 16);
      o.z = (unsigned)f2bf(b.x) | ((unsigned)f2bf(b.y) << 16);
      o.w = (unsigned)f2bf(b.z) | ((unsigned)f2bf(b.w) << 16);
      xd[i] = o;
    }
  }
  for (int i = tid; i < NEXP * HDIM / 4; i += 256)
    ((float4*)rws)[i] = ((const float4*)rw)[i];
  __syncthreads();
  {  // 256 (token,expert) dots, 1 per thread (x re-read hits L2)
    const int m = tid >> 3, e = tid & 7;
    const float* xr = x + (size_t)(t0 + m) * HDIM;
    const float* wr = rws + e * HDIM;
    float acc = 0.f;
    for (int h = 0; h < HDIM; h += 4) {
      float4 xv = *(const float4*)(xr + h);
      acc += xv.x * wr[h] + xv.y * wr[h + 1] + xv.z * wr[h + 2] + xv.w * wr[h + 3];
    }
    lg[m][e] = acc;
  }
  __syncthreads();
  if (tid < 32) {  // lanes 0..31 of wave 0: softmax + top2 + partials
    const int m = tid;
    float pr[8], mx = -1e30f;
    for (int e = 0; e < 8; e++) { pr[e] = lg[m][e]; mx = fmaxf(mx, pr[e]); }
    float s = 0.f;
    for (int e = 0; e < 8; e++) { pr[e] = __expf(pr[e] - mx); s += pr[e]; }
    float inv = 1.f / s;
    for (int e = 0; e < 8; e++) pr[e] *= inv;
    int i0 = 0;
    for (int e = 1; e < 8; e++) if (pr[e] > pr[i0]) i0 = e;
    int i1 = (i0 == 0) ? 1 : 0;
    for (int e = 0; e < 8; e++) if (e != i0 && pr[e] > pr[i1]) i1 = e;
    const int t = t0 + m;
    ((uchar2*)(ws + WS_TOPKI))[t] = make_uchar2((unsigned char)i0, (unsigned char)i1);
    ((float*)(ws + WS_TOPKP))[2 * t] = pr[i0];
    ((float*)(ws + WS_TOPKP))[2 * t + 1] = pr[i1];
    float* ip = (float*)(ws + WS_IMP) + blockIdx.x * 8;
    int* cp = (int*)(ws + WS_CNTP) + blockIdx.x * 8;
    for (int e = 0; e < 8; e++) {
      float v = pr[e];
      for (int off = 16; off; off >>= 1) v += __shfl_down(v, off);  // lanes 0..31
      unsigned long long b0 = __ballot(i0 == e);
      unsigned long long b1 = __ballot(i1 == e);
      if (tid == 0) { ip[e] = v; cp[e] = __popcll(b0) + __popcll(b1); }
    }
  }
}

// ---- finalize: PARALLEL partial reduction (64 thr), serial prefix tail -----
// 8 partials per expert x 32 blocks each; 3-step shfl_down tree is clean at
// the base lane of each 8-lane group (only base-lane results are consumed).
__global__ void finalize_kernel(char* __restrict__ ws) {
  __shared__ int scnt[8];
  const int tid = threadIdx.x;          // 64 threads, one wave
  const int e = tid >> 3, part = tid & 7;
  const float* ip = (const float*)(ws + WS_IMP);
  const int* cp = (const int*)(ws + WS_CNTP);
  float s = 0.f; int c = 0;
  for (int b = part * 32; b < part * 32 + 32; b++) {
    s += ip[b * 8 + e];
    c += cp[b * 8 + e];
  }
  for (int off = 4; off; off >>= 1) {
    s += __shfl_down(s, off);
    c += __shfl_down(c, off);
  }
  if (part == 0) {
    float running = 1.0f;
    float blended = running + 0.1f * (s - running);
    ((float*)(ws + WS_RUN))[e] = blended + 0.01f;
    ((int*)(ws + WS_CNT))[e] = c;
    ((int*)(ws + WS_CNT2))[e * 16] = 0;   // padded counters, 1 per cacheline
    scnt[e] = c;
  }
  __syncthreads();
  if (tid == 0) {
    int* offp = (int*)(ws + WS_OFFP);
    int* ttab = (int*)(ws + WS_TTAB);
    int o = 0, n = 0;
    for (int e2 = 0; e2 < 8; e2++) {
      offp[e2] = o;
      int tl = (scnt[e2] + BM - 1) / BM;
      o += tl * BM;
      for (int r = 0; r < tl; r++) ttab[n++] = (e2 << 8) | r;
    }
    *((int*)(ws + WS_NTIL)) = n;
  }
}

// ------- build lists: wave-aggregated ballot ranks, 1 atomic/(wave,expert) --
__global__ __launch_bounds__(256) void build_lists(char* __restrict__ ws) {
  const int t = blockIdx.x * blockDim.x + threadIdx.x;
  const int lane = threadIdx.x & 63;
  const uchar2* ti = (const uchar2*)(ws + WS_TOPKI);
  const float* tp = (const float*)(ws + WS_TOPKP);
  const float* run = (const float*)(ws + WS_RUN);
  int* cnt2 = (int*)(ws + WS_CNT2);
  const int* offp = (const int*)(ws + WS_OFFP);
  int* ltok = (int*)(ws + WS_LTOK);
  float* lw = (float*)(ws + WS_LW);
  const uchar2 ee = ti[t];
  const int e0 = ee.x, e1 = ee.y;
  const float b0 = tp[2 * t] / run[e0], b1 = tp[2 * t + 1] / run[e1];
  const float inv = 1.f / (b0 + b1);
  const unsigned long long lt = (1ull << lane) - 1ull;
  int g0 = 0, g1 = 0;
#pragma unroll
  for (int e = 0; e < 8; e++) {
    unsigned long long m0 = __ballot(e0 == e);
    unsigned long long m1 = __ballot(e1 == e);
    const int c0 = __popcll(m0);
    const int ctot = c0 + __popcll(m1);
    int base = 0;
    if (lane == 0 && ctot) base = atomicAdd(&cnt2[e * 16], ctot);
    base = __shfl(base, 0);
    if (e0 == e) g0 = offp[e] + base + __popcll(m0 & lt);
    if (e1 == e) g1 = offp[e] + base + c0 + __popcll(m1 & lt);
  }
  ltok[g0] = t; lw[g0] = b0 * inv;
  ltok[g1] = t; lw[g1] = b1 * inv;
  // overlay: WS_TG[t] occupies exactly tp[2t..2t+1] which this thread has read
  ((int2*)(ws + WS_TG))[t] = make_int2(g0, g1);
}

// ======== pipelined GEMM core (round-5 proven form, counted vmcnt) ========
#define GEMM_PIPELINE(NK)                                                      \
  {                                                                            \
    stage(0, 0);                                                               \
    stage(1, 1);                                                               \
    asm volatile("s_waitcnt vmcnt(8)" ::: "memory");                           \
    __builtin_amdgcn_sched_barrier(0);                                         \
    asm volatile("s_barrier" ::: "memory");                                    \
    int cur = 0;                                                               \
    for (int t = 0; t < (NK); ++t) {                                           \
      bf16x8 af[2][4], bg[2][4];                                               \
      const unsigned short* rA = &SB[cur][0][0];                               \
      const unsigned short* rB = &SB[cur][1][0];                               \
      _Pragma("unroll") for (int ks = 0; ks < 2; ks++) {                       \
        const int sl = ((ks * 4 + hi) ^ (fr & 7)) * 8;                         \
        _Pragma("unroll") for (int i = 0; i < 4; i++)                          \
            af[ks][i] = *(const bf16x8*)&rA[(wr + i * 16 + fr) * BK + sl];     \
        _Pragma("unroll") for (int j = 0; j < 4; j++)                          \
            bg[ks][j] = *(const bf16x8*)&rB[(wc + j * 16 + fr) * BK + sl];     \
      }                                                                        \
      asm volatile("s_waitcnt lgkmcnt(0)" ::: "memory"); /* my reads done */   \
      __builtin_amdgcn_sched_barrier(0);                                       \
      asm volatile("s_barrier" ::: "memory");            /* all reads done */  \
      if (t + 2 < (NK)) stage(cur, t + 2);                                     \
      __builtin_amdgcn_s_setprio(1);                                           \
      _Pragma("unroll") for (int ks = 0; ks < 2; ks++)                         \
          _Pragma("unroll") for (int i = 0; i < 4; i++)                        \
              _Pragma("unroll") for (int j = 0; j < 4; j++)                    \
                  acc[i][j] = __builtin_amdgcn_mfma_f32_16x16x32_bf16(         \
                      af[ks][i], bg[ks][j], acc[i][j], 0, 0, 0);               \
      __builtin_amdgcn_s_setprio(0);                                           \
      if (t + 2 < (NK)) {                                                      \
        asm volatile("s_waitcnt vmcnt(8)" ::: "memory"); /* t+1 landed */      \
      } else {                                                                 \
        asm volatile("s_waitcnt vmcnt(0)" ::: "memory"); /* tail drain */      \
      }                                                                        \
      __builtin_amdgcn_sched_barrier(0);                                       \
      asm volatile("s_barrier" ::: "memory");            /* t+1 ready */       \
      cur ^= 1;                                                                \
    }                                                                          \
  }

// ---------------- GEMM1: h = silu(x_gather @ w1_e^T), K=768 ----------------
__global__ __launch_bounds__(256) void gemm1_kernel(char* __restrict__ ws) {
  __shared__ unsigned short SB[2][2][BM * BK];  // 64KB: [dbuf][A/B][128][64]
  const int nt = *(const int*)(ws + WS_NTIL);
  const int nbx = IDIM / BN;                    // 16
  int bid = blockIdx.y * nbx + blockIdx.x;
  const int chunk = (nbx * MAXTILES) >> 3;      // 2176/8 = 272, bijective
  bid = (bid & 7) * chunk + (bid >> 3);
  const int bx = bid % nbx, by = bid / nbx;
  if (by >= nt) return;
  const int tile = ((const int*)(ws + WS_TTAB))[by];
  const int e = tile >> 8, rt = tile & 255;
  const int ce = ((const int*)(ws + WS_CNT))[e];
  const int base = ((const int*)(ws + WS_OFFP))[e];
  const int* __restrict__ ltok = (const int*)(ws + WS_LTOK);
  const unsigned short* __restrict__ xb = (const unsigned short*)(ws + WS_XB);
  const unsigned short* __restrict__ w1b =
      (const unsigned short*)(ws + WS_W1B) + (size_t)e * IDIM * HDIM;
  unsigned short* __restrict__ hb = (unsigned short*)(ws + WS_H);

  const int tid = threadIdx.x;
  const int lane = tid & 63, wave = tid >> 6;
  const int lr = tid >> 3;                               // staging row 0..31
  const int ko_sw = ((tid & 7) ^ (lr & 7)) * 8;          // source-side XOR swizzle
  const int n0 = bx * BN;

  const unsigned short* ga[4];
  const unsigned short* gb[4];
#pragma unroll
  for (int c = 0; c < 4; c++) {
    int s = rt * BM + c * 32 + lr; s = (s < ce) ? s : (ce - 1);
    ga[c] = xb + (size_t)ltok[base + s] * HDIM + ko_sw;
    gb[c] = w1b + (size_t)(n0 + c * 32 + lr) * HDIM + ko_sw;
  }

  auto stage = [&](int buf, int kt) {
    unsigned short* dA = &SB[buf][0][wave * 512];
    unsigned short* dB = &SB[buf][1][wave * 512];
#pragma unroll
    for (int c = 0; c < 4; c++) {
      gload_lds16(ga[c] + kt * BK, dA + c * 2048);
      gload_lds16(gb[c] + kt * BK, dB + c * 2048);
    }
  };

  f32x4 acc[4][4];
#pragma unroll
  for (int i = 0; i < 4; i++)
#pragma unroll
    for (int j = 0; j < 4; j++) acc[i][j] = (f32x4){0.f, 0.f, 0.f, 0.f};

  const int wr = (wave >> 1) * 64, wc = (wave & 1) * 64;
  const int fr = lane & 15, hi = lane >> 4;

  GEMM_PIPELINE(HDIM / BK)

  const int rq = (lane >> 4) * 4;
#pragma unroll
  for (int i = 0; i < 4; i++) {
#pragma unroll
    for (int r = 0; r < 4; r++) {
      const int slot = rt * BM + wr + i * 16 + rq + r;
      unsigned short* hrow = hb + (size_t)(base + slot) * IDIM + n0 + wc;
#pragma unroll
      for (int j = 0; j < 4; j++) {
        float v = acc[i][j][r];
        float sv = v / (1.f + __expf(-v));
        hrow[j * 16 + fr] = f2bf(sv);
      }
    }
  }
}

// ---------------- GEMM2: sel[g] = lw[g] * (h @ w2_e^T) (bf16), K=2048 ------
__global__ __launch_bounds__(256) void gemm2_kernel(char* __restrict__ ws) {
  __shared__ unsigned short SB[2][2][BM * BK];  // 64KB
  const int nt = *(const int*)(ws + WS_NTIL);
  const int nbx = HDIM / BN;                    // 6
  int bid = blockIdx.y * nbx + blockIdx.x;
  const int chunk = (nbx * MAXTILES) >> 3;      // 816/8 = 102, bijective
  bid = (bid & 7) * chunk + (bid >> 3);
  const int bx = bid % nbx, by = bid / nbx;
  if (by >= nt) return;
  const int tile = ((const int*)(ws + WS_TTAB))[by];
  const int e = tile >> 8, rt = tile & 255;
  const int ce = ((const int*)(ws + WS_CNT))[e];
  const int base = ((const int*)(ws + WS_OFFP))[e];
  const float* __restrict__ lw = (const float*)(ws + WS_LW);
  const unsigned short* __restrict__ hb = (const unsigned short*)(ws + WS_H);
  const unsigned short* __restrict__ w2b =
      (const unsigned short*)(ws + WS_W2B) + (size_t)e * HDIM * IDIM;
  unsigned short* __restrict__ selb = (unsigned short*)(ws + WS_SEL);

  const int tid = threadIdx.x;
  const int lane = tid & 63, wave = tid >> 6;
  const int lr = tid >> 3;
  const int ko_sw = ((tid & 7) ^ (lr & 7)) * 8;
  const int n0 = bx * BN;

  const unsigned short* ga[4];
  const unsigned short* gb[4];
#pragma unroll
  for (int c = 0; c < 4; c++) {
    ga[c] = hb + (size_t)(base + rt * BM + c * 32 + lr) * IDIM + ko_sw;  // pad rows defined
    gb[c] = w2b + (size_t)(n0 + c * 32 + lr) * IDIM + ko_sw;
  }

  auto stage = [&](int buf, int kt) {
    unsigned short* dA = &SB[buf][0][wave * 512];
    unsigned short* dB = &SB[buf][1][wave * 512];
#pragma unroll
    for (int c = 0; c < 4; c++) {
      gload_lds16(ga[c] + kt * BK, dA + c * 2048);
      gload_lds16(gb[c] + kt * BK, dB + c * 2048);
    }
  };

  f32x4 acc[4][4];
#pragma unroll
  for (int i = 0; i < 4; i++)
#pragma unroll
    for (int j = 0; j < 4; j++) acc[i][j] = (f32x4){0.f, 0.f, 0.f, 0.f};

  const int wr = (wave >> 1) * 64, wc = (wave & 1) * 64;
  const int fr = lane & 15, hi = lane >> 4;

  GEMM_PIPELINE(IDIM / BK)

  const int rq = (lane >> 4) * 4;
#pragma unroll
  for (int i = 0; i < 4; i++) {
#pragma unroll
    for (int r = 0; r < 4; r++) {
      const int slot = rt * BM + wr + i * 16 + rq + r;
      if (slot < ce) {
        const int g = base + slot;
        const float w = lw[g];                      // weight pre-applied before bf16
        unsigned short* srow = selb + (size_t)g * HDIM + n0 + wc;
#pragma unroll
        for (int j = 0; j < 4; j++)
          srow[j * 16 + fr] = f2bf(w * acc[i][j][r]);
      }
    }
  }
}

// ---------------- combine: out[t] = sel[g0] + sel[g1], 2 tokens/block -------
__global__ __launch_bounds__(384) void combine_kernel(const char* __restrict__ ws,
                                                      float* __restrict__ out) {
  const int t = blockIdx.x * 2 + (threadIdx.x >= 192);
  const int c = threadIdx.x - (threadIdx.x >= 192 ? 192 : 0);  // 0..191, 4 floats each
  const int2 g = ((const int2*)(ws + WS_TG))[t];
  const unsigned short* selb = (const unsigned short*)(ws + WS_SEL);
  ushort4 a = *(const ushort4*)(selb + (size_t)g.x * HDIM + c * 4);
  ushort4 b = *(const ushort4*)(selb + (size_t)g.y * HDIM + c * 4);
  float4 o;
  o.x = bf2f(a.x) + bf2f(b.x);
  o.y = bf2f(a.y) + bf2f(b.y);
  o.z = bf2f(a.z) + bf2f(b.z);
  o.w = bf2f(a.w) + bf2f(b.w);
  ((float4*)out)[(size_t)t * (HDIM / 4) + c] = o;
}

extern "C" void kernel_launch(void* const* d_in, const int* in_sizes, int n_in,
                              void* d_out, int out_size, void* d_ws, size_t ws_size,
                              hipStream_t stream) {
  const float* x = (const float*)d_in[0];
  const float* rw = (const float*)d_in[1];
  const float* w1 = (const float*)d_in[2];
  const float* w2 = (const float*)d_in[3];
  float* out = (float*)d_out;
  char* ws = (char*)d_ws;

  if (ws_size < (size_t)WS_NEEDED) {  // diagnostic path: zeros
    hipMemsetAsync(d_out, 0, (size_t)out_size * sizeof(float), stream);
    return;
  }

  cvt_w_kernel<<<2048, 256, 0, stream>>>(w1, w2, ws);
  router_kernel<<<NTOK / 32, 256, 0, stream>>>(x, rw, ws);
  finalize_kernel<<<1, 64, 0, stream>>>(ws);
  build_lists<<<NTOK / 256, 256, 0, stream>>>(ws);
  gemm1_kernel<<<dim3(IDIM / BN, MAXTILES), 256, 0, stream>>>(ws);
  gemm2_kernel<<<dim3(HDIM / BN, MAXTILES), 256, 0, stream>>>(ws);
  combine_kernel<<<NTOK / 2, 384, 0, stream>>>(ws, out);
}